// Round 1
// baseline (934.455 us; speedup 1.0000x reference)
//
#include <hip/hip_runtime.h>
#include <math.h>

// Problem constants (B=C=1)
#define NPAT 27          // 3^3 patches
#define PATCH 110592     // 48^3 voxels per patch
#define VOL 884736       // 96^3 grid voxels
#define GSBLK 128

__device__ __forceinline__ float softplusf(float a) {
    // stable softplus = max(a,0) + log1p(exp(-|a|)) — matches jax.nn.softplus
    return fmaxf(a, 0.f) + log1pf(expf(-fabsf(a)));
}

// One full Gauss-Seidel sweep over the 27 patches, fused with extract().
// Each thread owns one patch-voxel p; cur[27] lives in LDS (dynamic i index).
// A reads are the HBM-dominant stream: fully coalesced (p is innermost dim).
__global__ __launch_bounds__(GSBLK) void gs_sweep(
    const float* __restrict__ xf, const float* __restrict__ bg,
    const float* __restrict__ A, float* __restrict__ cur_out)
{
    __shared__ float cur[NPAT * GSBLK];   // 13.8 KB, slot-per-thread, no barriers needed
    const int tid = threadIdx.x;
    const int p = blockIdx.x * GSBLK + tid;      // grid = PATCH/GSBLK exactly
    const int pd = p / 2304;                     // 48*48
    const int r0 = p - pd * 2304;
    const int ph = r0 / 48;
    const int pw = r0 - ph * 48;
    const int gbase = (pd * 96 + ph) * 96 + pw;  // global idx for patch (0,0,0)

    // extract(): init cur[n] = x_field[lin(n,p)]
#pragma unroll
    for (int n = 0; n < NPAT; ++n) {
        const int nd = n / 9, nh = (n / 3) % 3, nw = n % 3;
        const int g = gbase + ((nd * 24) * 96 + nh * 24) * 96 + nw * 24;
        cur[n * GSBLK + tid] = xf[g];
    }

    const float* Ap = A + p;
#pragma unroll 1
    for (int i = 0; i < NPAT; ++i) {
        const float* Ai = Ap + (size_t)i * (NPAT * PATCH);
        float cross = 0.f;
#pragma unroll
        for (int n = 0; n < NPAT; ++n) {           // 27 independent loads -> MLP
            cross += Ai[(size_t)n * PATCH] * cur[n * GSBLK + tid];
        }
        const float aii = Ai[(size_t)i * PATCH];   // L1 hit (just streamed)
        const float xi = cur[i * GSBLK + tid];
        const int id = i / 9, ih = (i / 3) % 3, iw = i % 3;
        const int g = gbase + ((id * 24) * 96 + ih * 24) * 96 + iw * 24;
        const float bi = bg[g];
        const float coupling = cross - aii * xi;
        const float xnew = (bi - coupling) / (softplusf(aii) + 1e-8f);
        cur[i * GSBLK + tid] = xnew;
    }

#pragma unroll
    for (int n = 0; n < NPAT; ++n) {
        cur_out[(size_t)n * PATCH + p] = cur[n * GSBLK + tid];
    }
}

// reconstruct(): gather the <=8 covering patches per voxel, divide by coverage.
__global__ __launch_bounds__(256) void recon(
    const float* __restrict__ cur, float* __restrict__ out)
{
    const int g = blockIdx.x * 256 + threadIdx.x;
    const int gd = g / 9216;                 // 96*96
    const int r = g - gd * 9216;
    const int gh = r / 96;
    const int gw = r - gh * 96;
    const int dlo = max(0, gd / 24 - 1), dhi = min(2, gd / 24);
    const int hlo = max(0, gh / 24 - 1), hhi = min(2, gh / 24);
    const int wlo = max(0, gw / 24 - 1), whi = min(2, gw / 24);
    float sum = 0.f;
    for (int nd = dlo; nd <= dhi; ++nd)
        for (int nh = hlo; nh <= hhi; ++nh)
            for (int nw = wlo; nw <= whi; ++nw) {
                const int n = nd * 9 + nh * 3 + nw;
                const int pp = (gd - 24 * nd) * 2304 + (gh - 24 * nh) * 48 + (gw - 24 * nw);
                sum += cur[(size_t)n * PATCH + pp];
            }
    const int cnt = (dhi - dlo + 1) * (hhi - hlo + 1) * (whi - wlo + 1);
    out[g] = sum / (float)cnt;
}

// conv1 + relu: 1->16 channels, 3^3, pad 1. 4 outputs along w per thread.
__global__ __launch_bounds__(256) void conv1(
    const float* __restrict__ x, const float* __restrict__ w1,
    const float* __restrict__ b1, float* __restrict__ y1)
{
    const int t = blockIdx.x * 256 + threadIdx.x;
    const int g0 = t * 4;                    // 4 consecutive w outputs (96%4==0)
    const int gd = g0 / 9216;
    const int r = g0 - gd * 9216;
    const int gh = r / 96;
    const int gw = r - gh * 96;

    float xin[9][6];
#pragma unroll
    for (int kd = 0; kd < 3; ++kd)
#pragma unroll
        for (int kh = 0; kh < 3; ++kh) {
            const int d = gd + kd - 1, h = gh + kh - 1;
            const bool okdh = ((unsigned)d < 96u) && ((unsigned)h < 96u);
            const int rowbase = (d * 96 + h) * 96;
#pragma unroll
            for (int j = 0; j < 6; ++j) {
                const int wv = gw + j - 1;
                xin[kd * 3 + kh][j] =
                    (okdh && (unsigned)wv < 96u) ? x[rowbase + wv] : 0.f;
            }
        }

#pragma unroll
    for (int c = 0; c < 16; ++c) {
        const float bb = b1[c];
        float a0 = bb, a1 = bb, a2 = bb, a3 = bb;
#pragma unroll
        for (int kd = 0; kd < 3; ++kd)
#pragma unroll
            for (int kh = 0; kh < 3; ++kh)
#pragma unroll
                for (int kw = 0; kw < 3; ++kw) {
                    const float wgt = w1[c * 27 + kd * 9 + kh * 3 + kw]; // uniform -> s_load
                    const float* row = xin[kd * 3 + kh];
                    a0 += wgt * row[kw + 0];
                    a1 += wgt * row[kw + 1];
                    a2 += wgt * row[kw + 2];
                    a3 += wgt * row[kw + 3];
                }
        float4 v = make_float4(fmaxf(a0, 0.f), fmaxf(a1, 0.f),
                               fmaxf(a2, 0.f), fmaxf(a3, 0.f));
        *(float4*)&y1[(size_t)c * VOL + g0] = v;
    }
}

// conv2: 16->1 channels, 3^3, pad 1. 4 outputs along w per thread.
__global__ __launch_bounds__(256) void conv2(
    const float* __restrict__ y1, const float* __restrict__ w2,
    const float* __restrict__ b2, float* __restrict__ out)
{
    const int t = blockIdx.x * 256 + threadIdx.x;
    const int g0 = t * 4;
    const int gd = g0 / 9216;
    const int r = g0 - gd * 9216;
    const int gh = r / 96;
    const int gw = r - gh * 96;
    const float bb = b2[0];
    float a0 = bb, a1 = bb, a2 = bb, a3 = bb;

    for (int c = 0; c < 16; ++c) {
        const float* plane = y1 + (size_t)c * VOL;
        float xin[9][6];
#pragma unroll
        for (int kd = 0; kd < 3; ++kd)
#pragma unroll
            for (int kh = 0; kh < 3; ++kh) {
                const int d = gd + kd - 1, h = gh + kh - 1;
                const bool okdh = ((unsigned)d < 96u) && ((unsigned)h < 96u);
                const int rowbase = (d * 96 + h) * 96;
#pragma unroll
                for (int j = 0; j < 6; ++j) {
                    const int wv = gw + j - 1;
                    xin[kd * 3 + kh][j] =
                        (okdh && (unsigned)wv < 96u) ? plane[rowbase + wv] : 0.f;
                }
            }
#pragma unroll
        for (int kd = 0; kd < 3; ++kd)
#pragma unroll
            for (int kh = 0; kh < 3; ++kh)
#pragma unroll
                for (int kw = 0; kw < 3; ++kw) {
                    const float wgt = w2[c * 27 + kd * 9 + kh * 3 + kw];
                    const float* row = xin[kd * 3 + kh];
                    a0 += wgt * row[kw + 0];
                    a1 += wgt * row[kw + 1];
                    a2 += wgt * row[kw + 2];
                    a3 += wgt * row[kw + 3];
                }
    }
    *(float4*)&out[g0] = make_float4(a0, a1, a2, a3);
}

extern "C" void kernel_launch(void* const* d_in, const int* in_sizes, int n_in,
                              void* d_out, int out_size, void* d_ws, size_t ws_size,
                              hipStream_t stream)
{
    const float* x  = (const float*)d_in[0];
    const float* b  = (const float*)d_in[1];
    const float* A  = (const float*)d_in[2];
    const float* W1 = (const float*)d_in[3];
    const float* b1 = (const float*)d_in[4];
    const float* W2 = (const float*)d_in[5];
    const float* b2 = (const float*)d_in[6];
    float* out = (float*)d_out;

    // workspace partition (75.6 MB total)
    float* cur  = (float*)d_ws;                        // 27*PATCH
    float* xr   = cur + (size_t)NPAT * PATCH;          // VOL
    float* y1   = xr + VOL;                            // 16*VOL
    float* xnxt = y1 + (size_t)16 * VOL;               // VOL

    const int gsGrid = PATCH / GSBLK;   // 864
    const int rGrid  = VOL / 256;       // 3456
    const int cGrid  = VOL / 4 / 256;   // 864

    // iteration 1
    gs_sweep<<<gsGrid, GSBLK, 0, stream>>>(x, b, A, cur);
    recon<<<rGrid, 256, 0, stream>>>(cur, xr);
    conv1<<<cGrid, 256, 0, stream>>>(xr, W1, b1, y1);
    conv2<<<cGrid, 256, 0, stream>>>(y1, W2, b2, xnxt);
    // iteration 2
    gs_sweep<<<gsGrid, GSBLK, 0, stream>>>(xnxt, b, A, cur);
    recon<<<rGrid, 256, 0, stream>>>(cur, xr);
    conv1<<<cGrid, 256, 0, stream>>>(xr, W1, b1, y1);
    conv2<<<cGrid, 256, 0, stream>>>(y1, W2, b2, out);
}